// Round 1
// baseline (4188.757 us; speedup 1.0000x reference)
//
#include <hip/hip_runtime.h>
#include <hip/hip_bf16.h>

#define DIN 128

// ---------------- degree count ----------------
__global__ __launch_bounds__(256) void count_kernel(const int* __restrict__ dst,
                                                    float* __restrict__ cnt, int E) {
    int i = blockIdx.x * blockDim.x + threadIdx.x;
    if (i < E) {
        unsafeAtomicAdd(&cnt[dst[i]], 1.0f);
    }
}

__global__ __launch_bounds__(256) void inv_kernel(const float* __restrict__ cnt,
                                                  float* __restrict__ inv, int n) {
    int i = blockIdx.x * blockDim.x + threadIdx.x;
    if (i < n) inv[i] = 1.0f / fmaxf(cnt[i], 1.0f);
}

// ---------------- scatter-add of source features into dst rows ----------------
// one float4 chunk per work item; 32 chunks per edge (d=128)
__global__ __launch_bounds__(256) void scatter_kernel(const float* __restrict__ feat,
                                                      const int* __restrict__ src,
                                                      const int* __restrict__ dst,
                                                      float* __restrict__ agg, int E) {
    long long total = (long long)E * 32;
    long long stride = (long long)gridDim.x * blockDim.x;
    for (long long idx = (long long)blockIdx.x * blockDim.x + threadIdx.x; idx < total;
         idx += stride) {
        int e = (int)(idx >> 5);
        int q = (int)(idx & 31);
        int s = src[e], d = dst[e];
        float4 v = *reinterpret_cast<const float4*>(feat + (size_t)s * DIN + q * 4);
        float* a = agg + (size_t)d * DIN + q * 4;
        unsafeAtomicAdd(a + 0, v.x);
        unsafeAtomicAdd(a + 1, v.y);
        unsafeAtomicAdd(a + 2, v.z);
        unsafeAtomicAdd(a + 3, v.w);
    }
}

// ---------------- fused dual GEMM: out = (agg*inv)@Wl^T + x@Wr^T + b ----------------
// BM=64 rows/block, K=256 conceptual (128 agg-part + 128 x-part), 256 threads.
template <int DOUT, bool RELU>
__global__ __launch_bounds__(256) void sage_out_kernel(
    const float* __restrict__ agg, const float* __restrict__ xin,
    const float* __restrict__ inv_cnt,
    const float* __restrict__ Wl, const float* __restrict__ Wr,
    const float* __restrict__ bias, float* __restrict__ out, int n) {
    constexpr int BM = 64, KB = 16, TN = 8;
    constexpr int BN = DOUT;
    constexpr int CG = BN / TN;    // column groups (16 or 8)
    constexpr int RG = 256 / CG;   // row groups (16 or 32)
    constexpr int TM = BM / RG;    // 4 or 2

    __shared__ float As[BM][KB + 4];   // [m][k], 80B row stride (16B aligned)
    __shared__ float Bs[KB][BN + 4];   // [k][j]

    const int t = threadIdx.x;
    const int block_row = blockIdx.x * BM;

    const int tj = t % CG;
    const int tm = t / CG;

    float acc[TM][TN];
#pragma unroll
    for (int i = 0; i < TM; i++)
#pragma unroll
        for (int j = 0; j < TN; j++) acc[i][j] = 0.f;

    // A-tile load mapping: thread -> (row ar, 4 consecutive k at ak)
    const int ar = t >> 2;        // 0..63
    const int ak = (t & 3) * 4;   // 0,4,8,12
    const int arow = block_row + ar;
    const bool a_ok = arow < n;
    const float a_inv = a_ok ? inv_cnt[arow] : 0.f;
    const float* agg_row = agg + (size_t)arow * DIN;
    const float* x_row = xin + (size_t)arow * DIN;

    for (int kk = 0; kk < 2 * DIN; kk += KB) {
        // ---- load A tile ----
        float4 av = make_float4(0.f, 0.f, 0.f, 0.f);
        if (a_ok) {
            if (kk < DIN) {
                av = *reinterpret_cast<const float4*>(agg_row + kk + ak);
                av.x *= a_inv; av.y *= a_inv; av.z *= a_inv; av.w *= a_inv;
            } else {
                av = *reinterpret_cast<const float4*>(x_row + (kk - DIN) + ak);
            }
        }
        *reinterpret_cast<float4*>(&As[ar][ak]) = av;

        // ---- load B tile (W row-major [DOUT][128], need Bs[k][j] = W[j][kbase+k]) ----
        const float* W = (kk < DIN) ? Wl : Wr;
        const int kbase = (kk < DIN) ? kk : kk - DIN;
        if constexpr (BN == 128) {
            int j = t & 127;
            int kq = (t >> 7) * 8;  // 0 or 8
            float4 b0 = *reinterpret_cast<const float4*>(W + (size_t)j * DIN + kbase + kq);
            float4 b1 = *reinterpret_cast<const float4*>(W + (size_t)j * DIN + kbase + kq + 4);
            Bs[kq + 0][j] = b0.x; Bs[kq + 1][j] = b0.y; Bs[kq + 2][j] = b0.z; Bs[kq + 3][j] = b0.w;
            Bs[kq + 4][j] = b1.x; Bs[kq + 5][j] = b1.y; Bs[kq + 6][j] = b1.z; Bs[kq + 7][j] = b1.w;
        } else {
            int j = t & 63;
            int kq = (t >> 6) * 4;  // 0,4,8,12
            float4 b0 = *reinterpret_cast<const float4*>(W + (size_t)j * DIN + kbase + kq);
            Bs[kq + 0][j] = b0.x; Bs[kq + 1][j] = b0.y; Bs[kq + 2][j] = b0.z; Bs[kq + 3][j] = b0.w;
        }
        __syncthreads();

        // ---- FMA micro-tile ----
#pragma unroll
        for (int k = 0; k < KB; k++) {
            float a[TM];
#pragma unroll
            for (int i = 0; i < TM; i++) a[i] = As[tm * TM + i][k];
            float b[TN];
#pragma unroll
            for (int j = 0; j < TN; j++) b[j] = Bs[k][tj * TN + j];
#pragma unroll
            for (int i = 0; i < TM; i++)
#pragma unroll
                for (int j = 0; j < TN; j++) acc[i][j] = fmaf(a[i], b[j], acc[i][j]);
        }
        __syncthreads();
    }

    // ---- epilogue: bias (+ReLU) + store ----
    float bv[TN];
#pragma unroll
    for (int j = 0; j < TN; j++) bv[j] = bias[tj * TN + j];
#pragma unroll
    for (int i = 0; i < TM; i++) {
        int row = block_row + tm * TM + i;
        if (row < n) {
            float* orow = out + (size_t)row * DOUT + tj * TN;
#pragma unroll
            for (int j = 0; j < TN; j++) {
                float v = acc[i][j] + bv[j];
                if (RELU) v = fmaxf(v, 0.f);
                orow[j] = v;
            }
        }
    }
}

extern "C" void kernel_launch(void* const* d_in, const int* in_sizes, int n_in,
                              void* d_out, int out_size, void* d_ws, size_t ws_size,
                              hipStream_t stream) {
    const float* x = (const float*)d_in[0];
    const int* ei = (const int*)d_in[1];
    const float* W1l = (const float*)d_in[2];
    const float* b1 = (const float*)d_in[3];
    const float* W1r = (const float*)d_in[4];
    const float* W2l = (const float*)d_in[5];
    const float* b2 = (const float*)d_in[6];
    const float* W2r = (const float*)d_in[7];
    const float* W3l = (const float*)d_in[8];
    const float* b3 = (const float*)d_in[9];
    const float* W3r = (const float*)d_in[10];
    float* out = (float*)d_out;

    const int n = in_sizes[0] / DIN;   // 50000
    const int E = in_sizes[1] / 2;     // 800000
    const int* src = ei;
    const int* dst = ei + E;

    float* ws = (float*)d_ws;
    float* cnt = ws;                   // [n]
    float* inv = cnt + n;              // [n]
    float* agg = inv + n;              // [n*128]
    float* h1 = agg + (size_t)n * DIN; // [n*128]
    float* h2 = h1 + (size_t)n * DIN;  // [n*128]

    const int nb_edges = (E + 255) / 256;
    const int nb_nodes = (n + 255) / 256;
    const int nb_gemm = (n + 63) / 64;
    const int nb_scatter = 8192;

    // degree counts (reused for all 3 layers)
    hipMemsetAsync(cnt, 0, (size_t)n * sizeof(float), stream);
    count_kernel<<<nb_edges, 256, 0, stream>>>(dst, cnt, E);
    inv_kernel<<<nb_nodes, 256, 0, stream>>>(cnt, inv, n);

    // layer 1
    hipMemsetAsync(agg, 0, (size_t)n * DIN * sizeof(float), stream);
    scatter_kernel<<<nb_scatter, 256, 0, stream>>>(x, src, dst, agg, E);
    sage_out_kernel<128, true><<<nb_gemm, 256, 0, stream>>>(agg, x, inv, W1l, W1r, b1, h1, n);

    // layer 2
    hipMemsetAsync(agg, 0, (size_t)n * DIN * sizeof(float), stream);
    scatter_kernel<<<nb_scatter, 256, 0, stream>>>(h1, src, dst, agg, E);
    sage_out_kernel<128, true><<<nb_gemm, 256, 0, stream>>>(agg, h1, inv, W2l, W2r, b2, h2, n);

    // layer 3 (no relu), d_out = [n,64]
    hipMemsetAsync(agg, 0, (size_t)n * DIN * sizeof(float), stream);
    scatter_kernel<<<nb_scatter, 256, 0, stream>>>(h2, src, dst, agg, E);
    sage_out_kernel<64, false><<<nb_gemm, 256, 0, stream>>>(agg, h2, inv, W3l, W3r, b3, out, n);
}

// Round 2
// 428.440 us; speedup vs baseline: 9.7768x; 9.7768x over previous
//
#include <hip/hip_runtime.h>
#include <hip/hip_bf16.h>

#define DIN 128

// ================= CSR build =================
__global__ __launch_bounds__(256) void hist_kernel(const int* __restrict__ dst,
                                                   int* __restrict__ deg, int E) {
    int i = blockIdx.x * blockDim.x + threadIdx.x;
    if (i < E) atomicAdd(&deg[dst[i]], 1);
}

// per-block inclusive scan -> exclusive per element + block totals
__global__ __launch_bounds__(256) void scan1_kernel(const int* __restrict__ deg,
                                                    int* __restrict__ excl,
                                                    int* __restrict__ bsum, int n) {
    __shared__ int s[256];
    int t = threadIdx.x;
    int i = blockIdx.x * 256 + t;
    int v = (i < n) ? deg[i] : 0;
    s[t] = v;
    __syncthreads();
    for (int off = 1; off < 256; off <<= 1) {
        int add = (t >= off) ? s[t - off] : 0;
        __syncthreads();
        s[t] += add;
        __syncthreads();
    }
    if (i < n) excl[i] = s[t] - v;
    if (t == 255) bsum[blockIdx.x] = s[255];
}

// exclusive scan of block totals (nb <= 256)
__global__ __launch_bounds__(256) void scan2_kernel(const int* __restrict__ bsum,
                                                    int* __restrict__ boff, int nb) {
    __shared__ int s[256];
    int t = threadIdx.x;
    int v = (t < nb) ? bsum[t] : 0;
    s[t] = v;
    __syncthreads();
    for (int off = 1; off < 256; off <<= 1) {
        int add = (t >= off) ? s[t - off] : 0;
        __syncthreads();
        s[t] += add;
        __syncthreads();
    }
    if (t < nb) boff[t] = s[t] - v;
}

__global__ __launch_bounds__(256) void scan3_kernel(const int* __restrict__ excl,
                                                    const int* __restrict__ boff,
                                                    int* __restrict__ row_ptr,
                                                    int* __restrict__ cursor, int n, int E) {
    int i = blockIdx.x * 256 + threadIdx.x;
    if (i < n) {
        int r = excl[i] + boff[i >> 8];
        row_ptr[i] = r;
        cursor[i] = r;
    }
    if (i == n) row_ptr[n] = E;
}

__global__ __launch_bounds__(256) void fill_kernel(const int* __restrict__ src,
                                                   const int* __restrict__ dst,
                                                   int* __restrict__ cursor,
                                                   int* __restrict__ col, int E) {
    int i = blockIdx.x * blockDim.x + threadIdx.x;
    if (i < E) {
        int p = atomicAdd(&cursor[dst[i]], 1);
        col[p] = src[i];
    }
}

// ================= gather-aggregate (mean) =================
// one wave per node; lane owns 2 of 128 features; agg written pre-scaled by 1/max(deg,1)
__global__ __launch_bounds__(256) void aggregate_kernel(const float* __restrict__ feat,
                                                        const int* __restrict__ row_ptr,
                                                        const int* __restrict__ col,
                                                        float* __restrict__ agg, int n) {
    int node = (blockIdx.x << 2) + (threadIdx.x >> 6);
    if (node >= n) return;
    int lane = threadIdx.x & 63;
    int beg = row_ptr[node], end = row_ptr[node + 1];
    float2 a0 = make_float2(0.f, 0.f), a1 = make_float2(0.f, 0.f);
    int e = beg;
    for (; e + 2 <= end; e += 2) {
        int s0 = col[e], s1 = col[e + 1];
        float2 v0 = *reinterpret_cast<const float2*>(feat + (size_t)s0 * DIN + lane * 2);
        float2 v1 = *reinterpret_cast<const float2*>(feat + (size_t)s1 * DIN + lane * 2);
        a0.x += v0.x; a0.y += v0.y;
        a1.x += v1.x; a1.y += v1.y;
    }
    if (e < end) {
        int s0 = col[e];
        float2 v0 = *reinterpret_cast<const float2*>(feat + (size_t)s0 * DIN + lane * 2);
        a0.x += v0.x; a0.y += v0.y;
    }
    float sc = 1.0f / fmaxf((float)(end - beg), 1.0f);
    float2 r = make_float2((a0.x + a1.x) * sc, (a0.y + a1.y) * sc);
    *reinterpret_cast<float2*>(agg + (size_t)node * DIN + lane * 2) = r;
}

// ================= fused dual GEMM: out = agg@Wl^T + x@Wr^T + b =================
template <int DOUT, bool RELU>
__global__ __launch_bounds__(256) void sage_out_kernel(
    const float* __restrict__ agg, const float* __restrict__ xin,
    const float* __restrict__ Wl, const float* __restrict__ Wr,
    const float* __restrict__ bias, float* __restrict__ out, int n) {
    constexpr int BM = 64, KB = 16, TN = 8;
    constexpr int BN = DOUT;
    constexpr int CG = BN / TN;    // column groups (16 or 8)
    constexpr int RG = 256 / CG;   // row groups (16 or 32)
    constexpr int TM = BM / RG;    // 4 or 2

    __shared__ float As[BM][KB + 4];
    __shared__ float Bs[KB][BN + 4];

    const int t = threadIdx.x;
    const int block_row = blockIdx.x * BM;

    const int tj = t % CG;
    const int tm = t / CG;

    float acc[TM][TN];
#pragma unroll
    for (int i = 0; i < TM; i++)
#pragma unroll
        for (int j = 0; j < TN; j++) acc[i][j] = 0.f;

    const int ar = t >> 2;
    const int ak = (t & 3) * 4;
    const int arow = block_row + ar;
    const bool a_ok = arow < n;
    const float* agg_row = agg + (size_t)arow * DIN;
    const float* x_row = xin + (size_t)arow * DIN;

    for (int kk = 0; kk < 2 * DIN; kk += KB) {
        float4 av = make_float4(0.f, 0.f, 0.f, 0.f);
        if (a_ok) {
            if (kk < DIN) {
                av = *reinterpret_cast<const float4*>(agg_row + kk + ak);
            } else {
                av = *reinterpret_cast<const float4*>(x_row + (kk - DIN) + ak);
            }
        }
        *reinterpret_cast<float4*>(&As[ar][ak]) = av;

        const float* W = (kk < DIN) ? Wl : Wr;
        const int kbase = (kk < DIN) ? kk : kk - DIN;
        if constexpr (BN == 128) {
            int j = t & 127;
            int kq = (t >> 7) * 8;
            float4 b0 = *reinterpret_cast<const float4*>(W + (size_t)j * DIN + kbase + kq);
            float4 b1 = *reinterpret_cast<const float4*>(W + (size_t)j * DIN + kbase + kq + 4);
            Bs[kq + 0][j] = b0.x; Bs[kq + 1][j] = b0.y; Bs[kq + 2][j] = b0.z; Bs[kq + 3][j] = b0.w;
            Bs[kq + 4][j] = b1.x; Bs[kq + 5][j] = b1.y; Bs[kq + 6][j] = b1.z; Bs[kq + 7][j] = b1.w;
        } else {
            int j = t & 63;
            int kq = (t >> 6) * 4;
            float4 b0 = *reinterpret_cast<const float4*>(W + (size_t)j * DIN + kbase + kq);
            Bs[kq + 0][j] = b0.x; Bs[kq + 1][j] = b0.y; Bs[kq + 2][j] = b0.z; Bs[kq + 3][j] = b0.w;
        }
        __syncthreads();

#pragma unroll
        for (int k = 0; k < KB; k++) {
            float a[TM];
#pragma unroll
            for (int i = 0; i < TM; i++) a[i] = As[tm * TM + i][k];
            float b[TN];
#pragma unroll
            for (int j = 0; j < TN; j++) b[j] = Bs[k][tj * TN + j];
#pragma unroll
            for (int i = 0; i < TM; i++)
#pragma unroll
                for (int j = 0; j < TN; j++) acc[i][j] = fmaf(a[i], b[j], acc[i][j]);
        }
        __syncthreads();
    }

    float bv[TN];
#pragma unroll
    for (int j = 0; j < TN; j++) bv[j] = bias[tj * TN + j];
#pragma unroll
    for (int i = 0; i < TM; i++) {
        int row = block_row + tm * TM + i;
        if (row < n) {
            float* orow = out + (size_t)row * DOUT + tj * TN;
#pragma unroll
            for (int j = 0; j < TN; j++) {
                float v = acc[i][j] + bv[j];
                if (RELU) v = fmaxf(v, 0.f);
                orow[j] = v;
            }
        }
    }
}

extern "C" void kernel_launch(void* const* d_in, const int* in_sizes, int n_in,
                              void* d_out, int out_size, void* d_ws, size_t ws_size,
                              hipStream_t stream) {
    const float* x = (const float*)d_in[0];
    const int* ei = (const int*)d_in[1];
    const float* W1l = (const float*)d_in[2];
    const float* b1 = (const float*)d_in[3];
    const float* W1r = (const float*)d_in[4];
    const float* W2l = (const float*)d_in[5];
    const float* b2 = (const float*)d_in[6];
    const float* W2r = (const float*)d_in[7];
    const float* W3l = (const float*)d_in[8];
    const float* b3 = (const float*)d_in[9];
    const float* W3r = (const float*)d_in[10];
    float* out = (float*)d_out;

    const int n = in_sizes[0] / DIN;   // 50000
    const int E = in_sizes[1] / 2;     // 800000
    const int* src = ei;
    const int* dst = ei + E;

    // ---- workspace layout ----
    int* deg = (int*)d_ws;             // n
    int* excl = deg + n;               // n
    int* bsum = excl + n;              // 256
    int* boff = bsum + 256;            // 256
    int* row_ptr = boff + 256;         // n+1
    int* cursor = row_ptr + (n + 1);   // n
    int* col = cursor + n;             // E
    float* agg = (float*)(((uintptr_t)(col + E) + 255) & ~(uintptr_t)255);
    float* h1 = agg + (size_t)n * DIN;
    float* h2 = h1 + (size_t)n * DIN;

    const int nb_edges = (E + 255) / 256;
    const int nb_scan = (n + 255) / 256;         // 196
    const int nb_scan3 = (n + 256) / 256;        // covers i == n
    const int nb_agg = (n + 3) / 4;
    const int nb_gemm = (n + 63) / 64;

    // ---- CSR build ----
    hipMemsetAsync(deg, 0, (size_t)n * sizeof(int), stream);
    hist_kernel<<<nb_edges, 256, 0, stream>>>(dst, deg, E);
    scan1_kernel<<<nb_scan, 256, 0, stream>>>(deg, excl, bsum, n);
    scan2_kernel<<<1, 256, 0, stream>>>(bsum, boff, nb_scan);
    scan3_kernel<<<nb_scan3, 256, 0, stream>>>(excl, boff, row_ptr, cursor, n, E);
    fill_kernel<<<nb_edges, 256, 0, stream>>>(src, dst, cursor, col, E);

    // ---- layer 1 ----
    aggregate_kernel<<<nb_agg, 256, 0, stream>>>(x, row_ptr, col, agg, n);
    sage_out_kernel<128, true><<<nb_gemm, 256, 0, stream>>>(agg, x, W1l, W1r, b1, h1, n);

    // ---- layer 2 ----
    aggregate_kernel<<<nb_agg, 256, 0, stream>>>(h1, row_ptr, col, agg, n);
    sage_out_kernel<128, true><<<nb_gemm, 256, 0, stream>>>(agg, h1, W2l, W2r, b2, h2, n);

    // ---- layer 3 (no relu) ----
    aggregate_kernel<<<nb_agg, 256, 0, stream>>>(h2, row_ptr, col, agg, n);
    sage_out_kernel<64, false><<<nb_gemm, 256, 0, stream>>>(agg, h2, W3l, W3r, b3, out, n);
}

// Round 5
// 265.850 us; speedup vs baseline: 15.7561x; 1.6116x over previous
//
#include <hip/hip_runtime.h>
#include <hip/hip_bf16.h>

#define DIN 128

typedef __attribute__((ext_vector_type(8))) short short8;
typedef __attribute__((ext_vector_type(4))) float f32x4;
typedef __attribute__((ext_vector_type(4))) unsigned short ushort4v;

__device__ __forceinline__ unsigned short f2bf(float f) {
    unsigned int u = __float_as_uint(f);
    u += 0x7FFFu + ((u >> 16) & 1u);   // RNE
    return (unsigned short)(u >> 16);
}

// ================= dtype conversion =================
__global__ __launch_bounds__(256) void convert_x_kernel(const float* __restrict__ x,
                                                        unsigned short* __restrict__ xb,
                                                        int total4) {
    int i = blockIdx.x * 256 + threadIdx.x;   // 4 floats per thread
    if (i < total4) {
        float4 v = reinterpret_cast<const float4*>(x)[i];
        ushort4v o = {f2bf(v.x), f2bf(v.y), f2bf(v.z), f2bf(v.w)};
        reinterpret_cast<ushort4v*>(xb)[i] = o;
    }
}

// pack [Wl|Wr] (fp32, row-major [DOUT][128] each) into MFMA-fragment-ordered bf16:
// chunk (nt,ks) holds 64 lanes x 8 bf16; lane l covers W'[nt*16+(l&15)][ks*32+(l>>4)*8 ..+7]
template <int DOUT>
__global__ __launch_bounds__(256) void pack_w_kernel(const float* __restrict__ Wl,
                                                     const float* __restrict__ Wr,
                                                     unsigned short* __restrict__ Wp) {
    constexpr int NT = DOUT / 16;
    int idx = blockIdx.x * 256 + threadIdx.x;
    if (idx >= NT * 8 * 64) return;
    int l = idx & 63;
    int ts = idx >> 6;          // nt*8 + ks
    int ks = ts & 7;
    int nt = ts >> 3;
    int row = nt * 16 + (l & 15);
    int k = ks * 32 + ((l >> 4) << 3);   // 0..248, 8-aligned, never straddles 128
    const float* s = (k < 128) ? (Wl + (size_t)row * 128 + k)
                               : (Wr + (size_t)row * 128 + (k - 128));
    float4 v0 = *reinterpret_cast<const float4*>(s);
    float4 v1 = *reinterpret_cast<const float4*>(s + 4);
    unsigned short* d = Wp + (size_t)idx * 8;
    ushort4v o0 = {f2bf(v0.x), f2bf(v0.y), f2bf(v0.z), f2bf(v0.w)};
    ushort4v o1 = {f2bf(v1.x), f2bf(v1.y), f2bf(v1.z), f2bf(v1.w)};
    *reinterpret_cast<ushort4v*>(d) = o0;
    *reinterpret_cast<ushort4v*>(d + 4) = o1;
}

// ================= CSR build =================
__global__ __launch_bounds__(256) void hist_kernel(const int* __restrict__ dst,
                                                   int* __restrict__ deg, int E) {
    int i = blockIdx.x * blockDim.x + threadIdx.x;
    if (i < E) atomicAdd(&deg[dst[i]], 1);
}

__global__ __launch_bounds__(256) void scan1_kernel(const int* __restrict__ deg,
                                                    int* __restrict__ excl,
                                                    int* __restrict__ bsum, int n) {
    __shared__ int s[256];
    int t = threadIdx.x;
    int i = blockIdx.x * 256 + t;
    int v = (i < n) ? deg[i] : 0;
    s[t] = v;
    __syncthreads();
    for (int off = 1; off < 256; off <<= 1) {
        int add = (t >= off) ? s[t - off] : 0;
        __syncthreads();
        s[t] += add;
        __syncthreads();
    }
    if (i < n) excl[i] = s[t] - v;
    if (t == 255) bsum[blockIdx.x] = s[255];
}

__global__ __launch_bounds__(256) void scan2_kernel(const int* __restrict__ bsum,
                                                    int* __restrict__ boff, int nb) {
    __shared__ int s[256];
    int t = threadIdx.x;
    int v = (t < nb) ? bsum[t] : 0;
    s[t] = v;
    __syncthreads();
    for (int off = 1; off < 256; off <<= 1) {
        int add = (t >= off) ? s[t - off] : 0;
        __syncthreads();
        s[t] += add;
        __syncthreads();
    }
    if (t < nb) boff[t] = s[t] - v;
}

__global__ __launch_bounds__(256) void scan3_kernel(const int* __restrict__ excl,
                                                    const int* __restrict__ boff,
                                                    int* __restrict__ row_ptr,
                                                    int* __restrict__ cursor, int n, int E) {
    int i = blockIdx.x * 256 + threadIdx.x;
    if (i < n) {
        int r = excl[i] + boff[i >> 8];
        row_ptr[i] = r;
        cursor[i] = r;
    }
    if (i == n) row_ptr[n] = E;
}

__global__ __launch_bounds__(256) void fill_kernel(const int* __restrict__ src,
                                                   const int* __restrict__ dst,
                                                   int* __restrict__ cursor,
                                                   int* __restrict__ col, int E) {
    int i = blockIdx.x * blockDim.x + threadIdx.x;
    if (i < E) {
        int p = atomicAdd(&cursor[dst[i]], 1);
        col[p] = src[i];
    }
}

// ================= gather-aggregate (mean), bf16 in / bf16 out =================
// wave per node; lanes 0-31 even edges, 32-63 odd edges; each lane owns 4 features (8B loads)
__global__ __launch_bounds__(256) void aggregate_kernel(const unsigned short* __restrict__ feat,
                                                        const int* __restrict__ row_ptr,
                                                        const int* __restrict__ col,
                                                        unsigned short* __restrict__ agg, int n) {
    int node = (blockIdx.x << 2) + (threadIdx.x >> 6);
    if (node >= n) return;
    int lane = threadIdx.x & 63;
    int half = lane >> 5;
    int fb = (lane & 31) << 2;   // feature base (4 bf16 = 8B)
    int beg = row_ptr[node], end = row_ptr[node + 1];
    float s0 = 0.f, s1 = 0.f, s2 = 0.f, s3 = 0.f;
    float t0 = 0.f, t1 = 0.f, t2 = 0.f, t3 = 0.f;
    int e = beg + half;
    for (; e + 2 < end; e += 4) {
        int c0 = col[e], c1 = col[e + 2];
        uint2 v0 = *reinterpret_cast<const uint2*>(feat + (size_t)c0 * DIN + fb);
        uint2 v1 = *reinterpret_cast<const uint2*>(feat + (size_t)c1 * DIN + fb);
        s0 += __uint_as_float(v0.x << 16);
        s1 += __uint_as_float(v0.x & 0xFFFF0000u);
        s2 += __uint_as_float(v0.y << 16);
        s3 += __uint_as_float(v0.y & 0xFFFF0000u);
        t0 += __uint_as_float(v1.x << 16);
        t1 += __uint_as_float(v1.x & 0xFFFF0000u);
        t2 += __uint_as_float(v1.y << 16);
        t3 += __uint_as_float(v1.y & 0xFFFF0000u);
    }
    if (e < end) {
        int c0 = col[e];
        uint2 v0 = *reinterpret_cast<const uint2*>(feat + (size_t)c0 * DIN + fb);
        s0 += __uint_as_float(v0.x << 16);
        s1 += __uint_as_float(v0.x & 0xFFFF0000u);
        s2 += __uint_as_float(v0.y << 16);
        s3 += __uint_as_float(v0.y & 0xFFFF0000u);
    }
    s0 += t0; s1 += t1; s2 += t2; s3 += t3;
    s0 += __shfl_xor(s0, 32);
    s1 += __shfl_xor(s1, 32);
    s2 += __shfl_xor(s2, 32);
    s3 += __shfl_xor(s3, 32);
    if (half == 0) {
        float sc = 1.0f / fmaxf((float)(end - beg), 1.0f);
        ushort4v o = {f2bf(s0 * sc), f2bf(s1 * sc), f2bf(s2 * sc), f2bf(s3 * sc)};
        *reinterpret_cast<ushort4v*>(agg + (size_t)node * DIN + fb) = o;
    }
}

// ================= MFMA dual GEMM: out = [agg|x] @ Wp^T + b =================
// 4 waves/block, 16 rows/wave; K=256 (agg 0..127, x 128..255); no LDS.
template <int DOUT, bool RELU, bool OUTBF>
__global__ __launch_bounds__(256, 4) void mfma_gemm_kernel(
    const unsigned short* __restrict__ aggb, const unsigned short* __restrict__ xb,
    const unsigned short* __restrict__ Wp, const float* __restrict__ bias,
    void* __restrict__ outv, int n) {
    constexpr int NT = DOUT / 16;
    const int lane = threadIdx.x & 63;
    const int wave = threadIdx.x >> 6;
    const int row0 = blockIdx.x * 64 + wave * 16;
    const int ar = row0 + (lane & 15);
    const int kg = (lane >> 4) << 3;
    const bool ok = ar < n;

    const short8 z = {0, 0, 0, 0, 0, 0, 0, 0};
    short8 a[8];
    const unsigned short* arow = aggb + (size_t)ar * DIN + kg;
    const unsigned short* xrow = xb + (size_t)ar * DIN + kg;
#pragma unroll
    for (int ks = 0; ks < 4; ks++)
        a[ks] = ok ? *reinterpret_cast<const short8*>(arow + ks * 32) : z;
#pragma unroll
    for (int ks = 0; ks < 4; ks++)
        a[4 + ks] = ok ? *reinterpret_cast<const short8*>(xrow + ks * 32) : z;

    f32x4 acc[NT];
#pragma unroll
    for (int nt = 0; nt < NT; nt++) acc[nt] = {0.f, 0.f, 0.f, 0.f};

    const unsigned short* wp = Wp + ((size_t)lane << 3);
#pragma unroll
    for (int nt = 0; nt < NT; nt++) {
#pragma unroll
        for (int ks = 0; ks < 8; ks++) {
            short8 b = *reinterpret_cast<const short8*>(wp + ((size_t)(nt * 8 + ks) << 9));
            acc[nt] = __builtin_amdgcn_mfma_f32_16x16x32_bf16(a[ks], b, acc[nt], 0, 0, 0);
        }
    }

    // epilogue: D row=(lane>>4)*4+reg, col=nt*16+(lane&15)
    const int orow0 = row0 + ((lane >> 4) << 2);
#pragma unroll
    for (int nt = 0; nt < NT; nt++) {
        int c = nt * 16 + (lane & 15);
        float bv = bias[c];
#pragma unroll
        for (int rg = 0; rg < 4; rg++) {
            int rr = orow0 + rg;
            if (rr < n) {
                float v = acc[nt][rg] + bv;
                if (RELU) v = fmaxf(v, 0.f);
                if (OUTBF)
                    reinterpret_cast<unsigned short*>(outv)[(size_t)rr * DOUT + c] = f2bf(v);
                else
                    reinterpret_cast<float*>(outv)[(size_t)rr * DOUT + c] = v;
            }
        }
    }
}

extern "C" void kernel_launch(void* const* d_in, const int* in_sizes, int n_in,
                              void* d_out, int out_size, void* d_ws, size_t ws_size,
                              hipStream_t stream) {
    const float* x = (const float*)d_in[0];
    const int* ei = (const int*)d_in[1];
    const float* W1l = (const float*)d_in[2];
    const float* b1 = (const float*)d_in[3];
    const float* W1r = (const float*)d_in[4];
    const float* W2l = (const float*)d_in[5];
    const float* b2 = (const float*)d_in[6];
    const float* W2r = (const float*)d_in[7];
    const float* W3l = (const float*)d_in[8];
    const float* b3 = (const float*)d_in[9];
    const float* W3r = (const float*)d_in[10];
    float* out = (float*)d_out;

    const int n = in_sizes[0] / DIN;   // 50000
    const int E = in_sizes[1] / 2;     // 800000
    const int* src = ei;
    const int* dst = ei + E;

    // ---- workspace layout (256B-aligned sections) ----
    char* p = (char*)d_ws;
    auto take = [&](size_t bytes) {
        char* r = p;
        p += (bytes + 255) & ~(size_t)255;
        return r;
    };
    int* deg = (int*)take((size_t)n * 4);
    int* excl = (int*)take((size_t)n * 4);
    int* bsum = (int*)take(256 * 4);
    int* boff = (int*)take(256 * 4);
    int* row_ptr = (int*)take(((size_t)n + 1) * 4);
    int* cursor = (int*)take((size_t)n * 4);
    int* col = (int*)take((size_t)E * 4);
    unsigned short* xb = (unsigned short*)take((size_t)n * DIN * 2);
    unsigned short* aggb = (unsigned short*)take((size_t)n * DIN * 2);
    unsigned short* h1b = (unsigned short*)take((size_t)n * DIN * 2);
    unsigned short* h2b = (unsigned short*)take((size_t)n * DIN * 2);
    unsigned short* Wp1 = (unsigned short*)take(128 * 256 * 2);
    unsigned short* Wp2 = (unsigned short*)take(128 * 256 * 2);
    unsigned short* Wp3 = (unsigned short*)take(64 * 256 * 2);

    const int nb_edges = (E + 255) / 256;
    const int nb_scan = (n + 255) / 256;
    const int nb_scan3 = (n + 256) / 256;
    const int nb_agg = (n + 3) / 4;
    const int nb_gemm = (n + 63) / 64;
    const int nb_cvt = (n * 32 + 255) / 256;

    // ---- conversions (independent of CSR) ----
    convert_x_kernel<<<nb_cvt, 256, 0, stream>>>(x, xb, n * 32);
    pack_w_kernel<128><<<16, 256, 0, stream>>>(W1l, W1r, Wp1);
    pack_w_kernel<128><<<16, 256, 0, stream>>>(W2l, W2r, Wp2);
    pack_w_kernel<64><<<8, 256, 0, stream>>>(W3l, W3r, Wp3);

    // ---- CSR build ----
    hipMemsetAsync(deg, 0, (size_t)n * sizeof(int), stream);
    hist_kernel<<<nb_edges, 256, 0, stream>>>(dst, deg, E);
    scan1_kernel<<<nb_scan, 256, 0, stream>>>(deg, excl, bsum, n);
    scan2_kernel<<<1, 256, 0, stream>>>(bsum, boff, nb_scan);
    scan3_kernel<<<nb_scan3, 256, 0, stream>>>(excl, boff, row_ptr, cursor, n, E);
    fill_kernel<<<nb_edges, 256, 0, stream>>>(src, dst, cursor, col, E);

    // ---- layer 1 ----
    aggregate_kernel<<<nb_agg, 256, 0, stream>>>(xb, row_ptr, col, aggb, n);
    mfma_gemm_kernel<128, true, true><<<nb_gemm, 256, 0, stream>>>(aggb, xb, Wp1, b1, h1b, n);

    // ---- layer 2 ----
    aggregate_kernel<<<nb_agg, 256, 0, stream>>>(h1b, row_ptr, col, aggb, n);
    mfma_gemm_kernel<128, true, true><<<nb_gemm, 256, 0, stream>>>(aggb, h1b, Wp2, b2, h2b, n);

    // ---- layer 3 (no relu, fp32 out) ----
    aggregate_kernel<<<nb_agg, 256, 0, stream>>>(h2b, row_ptr, col, aggb, n);
    mfma_gemm_kernel<64, false, false><<<nb_gemm, 256, 0, stream>>>(aggb, h2b, Wp3, b3, out, n);
}